// Round 8
// baseline (3688.274 us; speedup 1.0000x reference)
//
#include <hip/hip_runtime.h>
#include <cmath>

// VanillaRNN: B=256, T=128, D=1, H=2048, C=10
// R8: persistent kernel. h-exchange: producers publish via sc1 (MALL
// write-through, no dirty L2 lines anywhere); consumers read via NORMAL
// cached loads after a per-step __builtin_amdgcn_fence(ACQUIRE, agent)
// (= buffer_inv, no wbl2 -- R4's tax was the wbl2 half). L2 absorbs the
// 64-consumer amplification (32 blocks/XCD share one MALL fill), load
// latency drops ~600 -> ~200 cyc, and the R7 LDS staging + 16 inner
// syncthreads are deleted (direct A-frag ring, depth-4/lookahead-3).
// W stays in ~256 VGPRs/lane as fp16 hi+lo. x staged once into LDS.
// Barrier: single-level 64-arrival per-m-group rails, per-step slots.

#define B_ 256
#define T_ 128
#define H_ 2048
#define C_ 10

typedef _Float16 half_t;
typedef _Float16 half8 __attribute__((ext_vector_type(8)));
typedef _Float16 half4v __attribute__((ext_vector_type(4)));
typedef float floatx4 __attribute__((ext_vector_type(4)));
typedef unsigned long long u64;

// barrier region (dword offsets; each counter on its own 128B line):
//   C0  [(t*4+g)*32]           : 64-block arrival count (m-group g, step t)
//   FLG [FLAG_OFF+(t*4+g)*32]  : release flag (m-group g, step t)
#define FLAG_OFF 16384
#define BAR_DWORDS 32768  // 128 KB

__device__ __forceinline__ void step_barrier(unsigned* bar, int t, int g) {
    __syncthreads();  // drains this block's sc1 h-stores (vmcnt0 before s_barrier)
    if (threadIdx.x == 0) {
        asm volatile("" ::: "memory");
        unsigned* c0 = bar + (t * 4 + g) * 32;
        unsigned* f  = bar + FLAG_OFF + (t * 4 + g) * 32;
        unsigned o = __hip_atomic_fetch_add(c0, 1u, __ATOMIC_RELAXED,
                                            __HIP_MEMORY_SCOPE_AGENT);
        if (o == 63u) {  // last block of the m-group: release
            __hip_atomic_store(f, 1u, __ATOMIC_RELAXED, __HIP_MEMORY_SCOPE_AGENT);
        } else {
            while (!__hip_atomic_load(f, __ATOMIC_RELAXED,
                                      __HIP_MEMORY_SCOPE_AGENT))
                __builtin_amdgcn_s_sleep(1);
        }
        asm volatile("" ::: "memory");
    }
    __syncthreads();
}

__device__ __forceinline__ float fast_tanh(float v) {
    return 1.0f - 2.0f / (__expf(2.0f * v) + 1.0f);
}

// ---- persistent RNN kernel ----
__global__ void __launch_bounds__(256, 1) rnn_persist(
    const float* __restrict__ x,   // [B_,T_]
    const float* __restrict__ U,   // [H_]
    const float* __restrict__ W,   // [H_,H_] fp32
    const float* __restrict__ bh,  // [H_]
    half_t* __restrict__ hA,       // ws state buf 0
    half_t* __restrict__ hB,       // ws state buf 1
    float* __restrict__ hf32,      // d_out h_last region
    unsigned* __restrict__ bar)
{
    const int tid  = threadIdx.x;
    const int wave = tid >> 6, lane = tid & 63;
    const int quad = lane >> 4, lq = lane & 15;
    const int id   = blockIdx.x;
    const int grp  = id & 7;
    const int g    = grp >> 1, p = grp & 1;
    const int m0   = g * 64;                      // m-group g owns 64 rows
    const int n0   = ((id >> 3) * 2 + p) * 32;    // 64 n-tiles of 32

    const int kw = wave * 32 + quad * 8;          // lane k base per 128-chunk

    // ---- one-time: W fragments -> registers (hi+lo fp16), ~256 regs ----
    half8 Bhi[16][2], Blo[16][2];
#pragma unroll
    for (int c = 0; c < 16; ++c) {
#pragma unroll
        for (int nt = 0; nt < 2; ++nt) {
            const int gn = n0 + nt * 16 + lq;
            const float4 w0 = *(const float4*)&W[(size_t)gn * H_ + c * 128 + kw];
            const float4 w1 = *(const float4*)&W[(size_t)gn * H_ + c * 128 + kw + 4];
            const float wv[8] = {w0.x, w0.y, w0.z, w0.w, w1.x, w1.y, w1.z, w1.w};
            half8 hi, lo;
#pragma unroll
            for (int j = 0; j < 8; ++j) {
                hi[j] = (half_t)wv[j];
                lo[j] = (half_t)(wv[j] - (float)hi[j]);
            }
            Bhi[c][nt] = hi;
            Blo[c][nt] = lo;
        }
    }

    float uv[2], bv[2];
#pragma unroll
    for (int nt = 0; nt < 2; ++nt) {
        uv[nt] = U[n0 + nt * 16 + lq];
        bv[nt] = bh[n0 + nt * 16 + lq];
    }
    const int gmb = m0 + wave * 16 + quad * 4;    // owner-lane 4 output rows
    const int lrow = wave * 16 + quad * 4;        // gmb - m0

    __shared__ floatx4 red[4][4][2][64];          // k-split reduction, 32 KB
    __shared__ float Sm[64][33];                  // epilogue transpose, 8.4 KB
    __shared__ float xs[T_][64];                  // x slab transposed, 32 KB

    // stage x[m0..m0+63][0..127] -> xs[t][r]  (one-time; conflict-free writes)
    for (int i = tid; i < 64 * T_; i += 256) {
        const int r = i & 63, tt = i >> 6;
        xs[tt][r] = x[(size_t)(m0 + r) * T_ + tt];
    }

    const int prow = tid >> 2;                    // pack thread: row 0..63
    const int pc0  = (tid & 3) * 8;               // 8-col chunk

    // ---- step 0: h1 = tanh(x[:,0]*U + bh)  (h0 = 0, no matmul) ----
    {
        const float xb = x[(size_t)(m0 + prow) * T_ + 0];
        const float4 u0 = *(const float4*)&U[n0 + pc0];
        const float4 u1 = *(const float4*)&U[n0 + pc0 + 4];
        const float4 b0 = *(const float4*)&bh[n0 + pc0];
        const float4 b1 = *(const float4*)&bh[n0 + pc0 + 4];
        const float uva[8] = {u0.x, u0.y, u0.z, u0.w, u1.x, u1.y, u1.z, u1.w};
        const float bva[8] = {b0.x, b0.y, b0.z, b0.w, b1.x, b1.y, b1.z, b1.w};
        half4v ha, hb2;
#pragma unroll
        for (int j = 0; j < 4; ++j) {
            ha[j]  = (half_t)fast_tanh(xb * uva[j] + bva[j]);
            hb2[j] = (half_t)fast_tanh(xb * uva[4 + j] + bva[4 + j]);
        }
        u64* dst = (u64*)(hB + (size_t)(m0 + prow) * H_ + n0 + pc0);
        __hip_atomic_store(dst, __builtin_bit_cast(u64, ha),
                           __ATOMIC_RELAXED, __HIP_MEMORY_SCOPE_AGENT);
        __hip_atomic_store(dst + 1, __builtin_bit_cast(u64, hb2),
                           __ATOMIC_RELAXED, __HIP_MEMORY_SCOPE_AGENT);
    }
    step_barrier(bar, 0, g);

    // ---- steps t = 1..127 ----
    for (int t = 1; t < T_; ++t) {
        const half_t* hin = (t & 1) ? hB : hA;    // h_t
        half_t* hout      = (t & 1) ? hA : hB;    // h_{t+1}

        // acquire: invalidate L1/L2 so cached h-loads see the MALL data
        // published before the barrier (no wbl2 -- nothing is ever dirty).
        __builtin_amdgcn_fence(__ATOMIC_ACQUIRE, "agent");

        floatx4 acc[4][2] = {};

        const half_t* base[4];
#pragma unroll
        for (int mt = 0; mt < 4; ++mt)
            base[mt] = hin + (size_t)(m0 + mt * 16 + lq) * H_ + kw;

        half8 ring[4][4];                         // depth-4, lookahead-3
        auto loadA = [&](half8* dst, int c) {
#pragma unroll
            for (int mt = 0; mt < 4; ++mt)
                dst[mt] = *(const half8*)(base[mt] + (size_t)c * 128);
        };
        loadA(ring[0], 0); loadA(ring[1], 1); loadA(ring[2], 2);
#pragma unroll
        for (int c = 0; c < 16; ++c) {
            if (c + 3 < 16) loadA(ring[(c + 3) & 3], c + 3);
            const half8* ac = ring[c & 3];
#pragma unroll
            for (int mt = 0; mt < 4; ++mt) {
                acc[mt][0] = __builtin_amdgcn_mfma_f32_16x16x32_f16(ac[mt], Bhi[c][0], acc[mt][0], 0, 0, 0);
                acc[mt][1] = __builtin_amdgcn_mfma_f32_16x16x32_f16(ac[mt], Bhi[c][1], acc[mt][1], 0, 0, 0);
                acc[mt][0] = __builtin_amdgcn_mfma_f32_16x16x32_f16(ac[mt], Blo[c][0], acc[mt][0], 0, 0, 0);
                acc[mt][1] = __builtin_amdgcn_mfma_f32_16x16x32_f16(ac[mt], Blo[c][1], acc[mt][1], 0, 0, 0);
            }
        }

        // ---- 4-way K-split reduction ----
#pragma unroll
        for (int mt = 0; mt < 4; ++mt)
#pragma unroll
            for (int nt = 0; nt < 2; ++nt)
                red[mt][wave][nt][lane] = acc[mt][nt];
        __syncthreads();

        // owner wave: sum, +x*U+bh, tanh -> Sm (fp32); x from LDS slab
        float xr[4];
#pragma unroll
        for (int r = 0; r < 4; ++r) xr[r] = xs[t][lrow + r];
#pragma unroll
        for (int nt = 0; nt < 2; ++nt) {
            const floatx4 s = red[wave][0][nt][lane] + red[wave][1][nt][lane]
                            + red[wave][2][nt][lane] + red[wave][3][nt][lane];
#pragma unroll
            for (int r = 0; r < 4; ++r) {
                const float pre = s[r] + xr[r] * uv[nt] + bv[nt];
                Sm[wave * 16 + quad * 4 + r][nt * 16 + lq] = fast_tanh(pre);
            }
        }
        __syncthreads();

        // pack 16B/thread, publish via 2x8B sc1 atomic stores
        {
            float fv[8];
#pragma unroll
            for (int j = 0; j < 8; ++j) fv[j] = Sm[prow][pc0 + j];
            half4v ha, hb2;
#pragma unroll
            for (int j = 0; j < 4; ++j) {
                ha[j] = (half_t)fv[j];
                hb2[j] = (half_t)fv[4 + j];
            }
            u64* dst = (u64*)(hout + (size_t)(m0 + prow) * H_ + n0 + pc0);
            __hip_atomic_store(dst, __builtin_bit_cast(u64, ha),
                               __ATOMIC_RELAXED, __HIP_MEMORY_SCOPE_AGENT);
            __hip_atomic_store(dst + 1, __builtin_bit_cast(u64, hb2),
                               __ATOMIC_RELAXED, __HIP_MEMORY_SCOPE_AGENT);
            if (t == T_ - 1) {
                // final fp32 h_last via sc1 u64 stores too: keeps the
                // no-dirty-L2-lines invariant (inv never discards data)
                u64* fd = (u64*)(hf32 + (size_t)(m0 + prow) * H_ + n0 + pc0);
#pragma unroll
                for (int j = 0; j < 4; ++j) {
                    double dv;
                    float2 f2 = make_float2(fv[2 * j], fv[2 * j + 1]);
                    dv = __builtin_bit_cast(double, f2);
                    __hip_atomic_store(fd + j, __builtin_bit_cast(u64, dv),
                                       __ATOMIC_RELAXED, __HIP_MEMORY_SCOPE_AGENT);
                }
            }
        }
        if (t < T_ - 1) step_barrier(bar, t, g);
    }
}

// ---- output projection: out[b,c] = h[b,:] . V[c,:] + bp[c] ----
__global__ __launch_bounds__(256) void rnn_out(
    const float* __restrict__ h, const float* __restrict__ V,
    const float* __restrict__ bp, float* __restrict__ outp) {
    const int b = blockIdx.x;
    const int tid = threadIdx.x;
    float acc[C_] = {};
    for (int k = tid; k < H_; k += 256) {
        const float hv = h[(size_t)b * H_ + k];
#pragma unroll
        for (int c = 0; c < C_; ++c) acc[c] += hv * V[(size_t)c * H_ + k];
    }
#pragma unroll
    for (int c = 0; c < C_; ++c)
#pragma unroll
        for (int off = 32; off > 0; off >>= 1)
            acc[c] += __shfl_down(acc[c], off, 64);
    __shared__ float partial[4][C_];
    const int wave = tid >> 6, lane = tid & 63;
    if (lane == 0)
#pragma unroll
        for (int c = 0; c < C_; ++c) partial[wave][c] = acc[c];
    __syncthreads();
    if (tid < C_)
        outp[b * C_ + tid] = partial[0][tid] + partial[1][tid]
                           + partial[2][tid] + partial[3][tid] + bp[tid];
}

extern "C" void kernel_launch(void* const* d_in, const int* in_sizes, int n_in,
                              void* d_out, int out_size, void* d_ws, size_t ws_size,
                              hipStream_t stream) {
    const float* x  = (const float*)d_in[0];
    const float* U  = (const float*)d_in[1];
    const float* W  = (const float*)d_in[2];
    const float* V  = (const float*)d_in[3];
    const float* bh = (const float*)d_in[4];
    const float* bp = (const float*)d_in[5];

    float* out_h = (float*)d_out;                 // [B_*H_] fp32 h_last
    float* outp  = out_h + (size_t)B_ * H_;       // [B_*C_]

    half_t* hA = (half_t*)d_ws;                                  // 1 MB
    half_t* hB = hA + (size_t)B_ * H_;                           // 1 MB
    unsigned* bar = (unsigned*)((char*)d_ws + 2u * 1024 * 1024); // 128 KB

    hipMemsetAsync(bar, 0, BAR_DWORDS * sizeof(unsigned), stream);

    rnn_persist<<<dim3(256), dim3(256), 0, stream>>>(
        x, U, W, bh, hA, hB, out_h, bar);

    rnn_out<<<dim3(B_), dim3(256), 0, stream>>>(out_h, V, bp, outp);
}

// Round 9
// 1774.606 us; speedup vs baseline: 2.0784x; 2.0784x over previous
//
#include <hip/hip_runtime.h>
#include <cmath>

// VanillaRNN: B=256, T=128, D=1, H=2048, C=10
// R9: persistent kernel, fence-free sc1 h-exchange (R6/R7 semantics; R8's
// per-step acquire-inv cost ~14us/step and is abandoned). NEW: h is stored
// in MFMA-FRAGMENT-PACKED layout, unit u (16B) = (c*16+w*4+mt)*64+lane per
// 256KB m-group slab. Consumer wave frag load = 1KB contiguous (16 dense
// 64B lines) straight into registers -- no LDS staging, no inner barriers;
// flat ring-8 over 64 frags hides MALL latency behind MFMAs. Producer
// publish = one contiguous 4KB region per block, 16B/thread.
// W in ~256 regs/lane as fp16 hi+lo. Barrier: per-m-group 2-level
// (8 rails x 8 + 8), per-step slots, relaxed agent atomics.

#define B_ 256
#define T_ 128
#define H_ 2048
#define C_ 10

typedef _Float16 half_t;
typedef _Float16 half8 __attribute__((ext_vector_type(8)));
typedef float floatx4 __attribute__((ext_vector_type(4)));
typedef unsigned long long u64;
typedef unsigned long long u64x2 __attribute__((ext_vector_type(2)));

// barrier region (dword offsets; each counter on its own 128B line):
//   C0  [((t*4+g)*8 + r)*32] : 8-block arrival count (rail r of m-group g)
//   C1  [C1_OFF+(t*4+g)*32]  : rail-leader count (8 arrivals)
//   FLG [FLAG_OFF+((t*4+g)*8+r)*32] : release flag per rail
#define C0_SZ   131072
#define C1_OFF  131072
#define C1_SZ   16384
#define FLAG_OFF 147456
#define BAR_DWORDS 278528   // ~1.06 MB

__device__ __forceinline__ void step_barrier(unsigned* bar, int t, int g, int r) {
    __syncthreads();  // drains this block's sc1 h-stores (vmcnt0 before s_barrier)
    if (threadIdx.x == 0) {
        asm volatile("" ::: "memory");
        unsigned* c0 = bar + ((t * 4 + g) * 8 + r) * 32;
        unsigned* f  = bar + FLAG_OFF + ((t * 4 + g) * 8 + r) * 32;
        unsigned o = __hip_atomic_fetch_add(c0, 1u, __ATOMIC_RELAXED,
                                            __HIP_MEMORY_SCOPE_AGENT);
        if (o == 7u) {  // rail leader
            unsigned* c1 = bar + C1_OFF + (t * 4 + g) * 32;
            unsigned o2 = __hip_atomic_fetch_add(c1, 1u, __ATOMIC_RELAXED,
                                                 __HIP_MEMORY_SCOPE_AGENT);
            if (o2 == 7u) {  // last rail: release all 8 rails of (t,g)
#pragma unroll
                for (int rr = 0; rr < 8; ++rr)
                    __hip_atomic_store(bar + FLAG_OFF + ((t * 4 + g) * 8 + rr) * 32,
                                       1u, __ATOMIC_RELAXED, __HIP_MEMORY_SCOPE_AGENT);
            } else {
                while (!__hip_atomic_load(f, __ATOMIC_RELAXED,
                                          __HIP_MEMORY_SCOPE_AGENT))
                    __builtin_amdgcn_s_sleep(1);
            }
        } else {
            while (!__hip_atomic_load(f, __ATOMIC_RELAXED,
                                      __HIP_MEMORY_SCOPE_AGENT))
                __builtin_amdgcn_s_sleep(1);
        }
        asm volatile("" ::: "memory");
    }
    __syncthreads();
}

__device__ __forceinline__ float fast_tanh(float v) {
    return 1.0f - 2.0f / (__expf(2.0f * v) + 1.0f);
}

// ---- persistent RNN kernel ----
__global__ void __launch_bounds__(256, 1) rnn_persist(
    const float* __restrict__ x,   // [B_,T_]
    const float* __restrict__ U,   // [H_]
    const float* __restrict__ W,   // [H_,H_] fp32
    const float* __restrict__ bh,  // [H_]
    half_t* __restrict__ hP0,      // packed state buf 0 (1 MB)
    half_t* __restrict__ hP1,      // packed state buf 1 (1 MB)
    float* __restrict__ hf32,      // d_out h_last region (row-major fp32)
    unsigned* __restrict__ bar)
{
    const int tid  = threadIdx.x;
    const int wave = tid >> 6, lane = tid & 63;
    const int quad = lane >> 4, lq = lane & 15;
    const int id   = blockIdx.x;
    const int grp  = id & 7;
    const int g    = grp >> 1, p = grp & 1;
    const int m0   = g * 64;                      // m-group g owns rows m0..m0+63
    const int C    = (id >> 3) * 2 + p;           // n-chunk 0..63; n0 = C*32
    const int n0   = C * 32;
    const int rail = (id >> 3) & 7;               // barrier sub-rail

    const int kw = wave * 32 + quad * 8;          // lane k base per 128-chunk

    // ---- one-time: W fragments -> registers (hi+lo fp16), ~256 regs ----
    half8 Bhi[16][2], Blo[16][2];
#pragma unroll
    for (int c = 0; c < 16; ++c) {
#pragma unroll
        for (int nt = 0; nt < 2; ++nt) {
            const int gn = n0 + nt * 16 + lq;
            const float4 w0 = *(const float4*)&W[(size_t)gn * H_ + c * 128 + kw];
            const float4 w1 = *(const float4*)&W[(size_t)gn * H_ + c * 128 + kw + 4];
            const float wv[8] = {w0.x, w0.y, w0.z, w0.w, w1.x, w1.y, w1.z, w1.w};
            half8 hi, lo;
#pragma unroll
            for (int j = 0; j < 8; ++j) {
                hi[j] = (half_t)wv[j];
                lo[j] = (half_t)(wv[j] - (float)hi[j]);
            }
            Bhi[c][nt] = hi;
            Blo[c][nt] = lo;
        }
    }

    float uv[2], bv[2];
#pragma unroll
    for (int nt = 0; nt < 2; ++nt) {
        uv[nt] = U[n0 + nt * 16 + lq];
        bv[nt] = bh[n0 + nt * 16 + lq];
    }

    __shared__ floatx4 red[4][4][2][64];          // k-split reduction, 32 KB
    __shared__ float Sm[64][33];                  // epilogue transpose, 8.4 KB
    __shared__ float xs[T_][64];                  // x slab transposed, 32 KB

    for (int i = tid; i < 64 * T_; i += 256) {    // one-time x staging
        const int r = i & 63, tt = i >> 6;
        xs[tt][r] = x[(size_t)(m0 + r) * T_ + tt];
    }
    __syncthreads();

    // producer thread mapping (fixed all steps):
    const int pmt = tid >> 6, pq = (tid >> 4) & 3, plq = tid & 15;
    const int prow = pmt * 16 + plq;              // local row 0..63
    const int pcol = pq * 8;                      // local col base (of 32)
    // packed slab offsets (u64 units; slab = g*32768)
    const size_t slab  = (size_t)g * 32768;
    const size_t pdst  = slab + ((size_t)C * 256 + tid) * 2;
    const size_t cbase = slab + (size_t)(wave * 4) * 128 + (size_t)lane * 2;

    // ---- step 0: h1 = tanh(x*U + bh) -> packed hP1 ----
    {
        const float xb = xs[0][prow];
        half8 hv;
#pragma unroll
        for (int j = 0; j < 8; ++j) {
            const int n = n0 + pcol + j;
            hv[j] = (half_t)fast_tanh(xb * U[n] + bh[n]);
        }
        const u64x2 bits = __builtin_bit_cast(u64x2, hv);
        u64* dst = (u64*)hP1 + pdst;
        __hip_atomic_store(dst, bits.x, __ATOMIC_RELAXED, __HIP_MEMORY_SCOPE_AGENT);
        __hip_atomic_store(dst + 1, bits.y, __ATOMIC_RELAXED, __HIP_MEMORY_SCOPE_AGENT);
    }
    step_barrier(bar, 0, g, rail);

    // ---- steps t = 1..127 ----
    for (int t = 1; t < T_; ++t) {
        const half_t* hin = (t & 1) ? hP1 : hP0;  // h_t (packed)
        half_t* hout      = (t & 1) ? hP0 : hP1;  // h_{t+1} (packed)
        const u64* pw = (const u64*)hin + cbase;

        floatx4 acc[4][2] = {};

        u64 rl[8], rh[8];                         // ring-8 of 16B frags
        auto issue = [&](int f) {
            const u64* q = pw + (size_t)(((f >> 2) * 16 + (f & 3)) * 128);
            rl[f & 7] = __hip_atomic_load(q, __ATOMIC_RELAXED,
                                          __HIP_MEMORY_SCOPE_AGENT);
            rh[f & 7] = __hip_atomic_load(q + 1, __ATOMIC_RELAXED,
                                          __HIP_MEMORY_SCOPE_AGENT);
        };
#pragma unroll
        for (int f = 0; f < 8; ++f) issue(f);
#pragma unroll
        for (int f = 0; f < 64; ++f) {
            const int c = f >> 2, mt = f & 3;
            u64x2 bits; bits.x = rl[f & 7]; bits.y = rh[f & 7];
            const half8 av = __builtin_bit_cast(half8, bits);
            if (f + 8 < 64) issue(f + 8);
            acc[mt][0] = __builtin_amdgcn_mfma_f32_16x16x32_f16(av, Bhi[c][0], acc[mt][0], 0, 0, 0);
            acc[mt][1] = __builtin_amdgcn_mfma_f32_16x16x32_f16(av, Bhi[c][1], acc[mt][1], 0, 0, 0);
            acc[mt][0] = __builtin_amdgcn_mfma_f32_16x16x32_f16(av, Blo[c][0], acc[mt][0], 0, 0, 0);
            acc[mt][1] = __builtin_amdgcn_mfma_f32_16x16x32_f16(av, Blo[c][1], acc[mt][1], 0, 0, 0);
        }

        // ---- 4-way K-split reduction ----
#pragma unroll
        for (int mt = 0; mt < 4; ++mt)
#pragma unroll
            for (int nt = 0; nt < 2; ++nt)
                red[mt][wave][nt][lane] = acc[mt][nt];
        __syncthreads();

        // owner wave (msub == wave): sum, +x*U+bh, tanh -> Sm
        const int lrow = wave * 16 + quad * 4;
        float xr[4];
#pragma unroll
        for (int r = 0; r < 4; ++r) xr[r] = xs[t][lrow + r];
#pragma unroll
        for (int nt = 0; nt < 2; ++nt) {
            const floatx4 s = red[wave][0][nt][lane] + red[wave][1][nt][lane]
                            + red[wave][2][nt][lane] + red[wave][3][nt][lane];
#pragma unroll
            for (int r = 0; r < 4; ++r) {
                const float pre = s[r] + xr[r] * uv[nt] + bv[nt];
                Sm[lrow + r][nt * 16 + lq] = fast_tanh(pre);
            }
        }
        __syncthreads();

        // publish: 16B/thread into the packed slab (contiguous 4KB/block)
        {
            float fv[8];
#pragma unroll
            for (int j = 0; j < 8; ++j) fv[j] = Sm[prow][pcol + j];
            half8 hv;
#pragma unroll
            for (int j = 0; j < 8; ++j) hv[j] = (half_t)fv[j];
            const u64x2 bits = __builtin_bit_cast(u64x2, hv);
            u64* dst = (u64*)hout + pdst;
            __hip_atomic_store(dst, bits.x, __ATOMIC_RELAXED, __HIP_MEMORY_SCOPE_AGENT);
            __hip_atomic_store(dst + 1, bits.y, __ATOMIC_RELAXED, __HIP_MEMORY_SCOPE_AGENT);
            if (t == T_ - 1) {  // final h_128 also to d_out, row-major fp32
                float* fd = hf32 + (size_t)(m0 + prow) * H_ + n0 + pcol;
                *(float4*)fd = make_float4(fv[0], fv[1], fv[2], fv[3]);
                *(float4*)(fd + 4) = make_float4(fv[4], fv[5], fv[6], fv[7]);
            }
        }
        if (t < T_ - 1) step_barrier(bar, t, g, rail);
    }
}

// ---- output projection: out[b,c] = h[b,:] . V[c,:] + bp[c] ----
__global__ __launch_bounds__(256) void rnn_out(
    const float* __restrict__ h, const float* __restrict__ V,
    const float* __restrict__ bp, float* __restrict__ outp) {
    const int b = blockIdx.x;
    const int tid = threadIdx.x;
    float acc[C_] = {};
    for (int k = tid; k < H_; k += 256) {
        const float hv = h[(size_t)b * H_ + k];
#pragma unroll
        for (int c = 0; c < C_; ++c) acc[c] += hv * V[(size_t)c * H_ + k];
    }
#pragma unroll
    for (int c = 0; c < C_; ++c)
#pragma unroll
        for (int off = 32; off > 0; off >>= 1)
            acc[c] += __shfl_down(acc[c], off, 64);
    __shared__ float partial[4][C_];
    const int wave = tid >> 6, lane = tid & 63;
    if (lane == 0)
#pragma unroll
        for (int c = 0; c < C_; ++c) partial[wave][c] = acc[c];
    __syncthreads();
    if (tid < C_)
        outp[b * C_ + tid] = partial[0][tid] + partial[1][tid]
                           + partial[2][tid] + partial[3][tid] + bp[tid];
}

extern "C" void kernel_launch(void* const* d_in, const int* in_sizes, int n_in,
                              void* d_out, int out_size, void* d_ws, size_t ws_size,
                              hipStream_t stream) {
    const float* x  = (const float*)d_in[0];
    const float* U  = (const float*)d_in[1];
    const float* W  = (const float*)d_in[2];
    const float* V  = (const float*)d_in[3];
    const float* bh = (const float*)d_in[4];
    const float* bp = (const float*)d_in[5];

    float* out_h = (float*)d_out;                 // [B_*H_] fp32 h_last
    float* outp  = out_h + (size_t)B_ * H_;       // [B_*C_]

    half_t* hP0 = (half_t*)d_ws;                                 // 1 MB packed
    half_t* hP1 = hP0 + (size_t)B_ * H_;                         // 1 MB packed
    unsigned* bar = (unsigned*)((char*)d_ws + 2u * 1024 * 1024); // ~1.06 MB

    hipMemsetAsync(bar, 0, BAR_DWORDS * sizeof(unsigned), stream);

    rnn_persist<<<dim3(256), dim3(256), 0, stream>>>(
        x, U, W, bh, hP0, hP1, out_h, bar);

    rnn_out<<<dim3(B_), dim3(256), 0, stream>>>(out_h, V, bp, outp);
}

// Round 10
// 1083.555 us; speedup vs baseline: 3.4039x; 1.6378x over previous
//
#include <hip/hip_runtime.h>
#include <cmath>

// VanillaRNN: B=256, T=128, D=1, H=2048, C=10
// R10: persistent kernel, fence-free sc1 packed h-exchange (R9), but
// 512-THREAD BLOCKS = 8 waves = 2 waves/SIMD (R6..R9 all ran 1 wave/SIMD;
// serial-latency-bound). W slice now 128 VGPRs/lane (hi+lo fp16), 8-way
// K-split (wave w owns K-steps w*8..w*8+8), reduction red[4][8][2][64],
// epilogue ownership (msub,nt)=(w&3,w>>2). Grid stays 256 = 1 block/CU.
// Packed slab layout unchanged: frag(K,mt) u64 = slab + K*512+mt*128+lane*2;
// producer u64 = slab + C*512 + tid (same algebra, wave-count-agnostic).

#define B_ 256
#define T_ 128
#define H_ 2048
#define C_ 10

typedef _Float16 half_t;
typedef _Float16 half8 __attribute__((ext_vector_type(8)));
typedef _Float16 half4v __attribute__((ext_vector_type(4)));
typedef float floatx4 __attribute__((ext_vector_type(4)));
typedef unsigned long long u64;
typedef unsigned long long u64x2 __attribute__((ext_vector_type(2)));

// barrier region (dword offsets; each counter on its own 128B line):
//   C0  [((t*4+g)*8 + r)*32] : 8-block arrival count (rail r of m-group g)
//   C1  [C1_OFF+(t*4+g)*32]  : rail-leader count (8 arrivals)
//   FLG [FLAG_OFF+((t*4+g)*8+r)*32] : release flag per rail
#define C1_OFF  131072
#define FLAG_OFF 147456
#define BAR_DWORDS 278528   // ~1.06 MB

__device__ __forceinline__ void step_barrier(unsigned* bar, int t, int g, int r) {
    __syncthreads();  // drains this block's sc1 h-stores (vmcnt0 before s_barrier)
    if (threadIdx.x == 0) {
        asm volatile("" ::: "memory");
        unsigned* c0 = bar + ((t * 4 + g) * 8 + r) * 32;
        unsigned* f  = bar + FLAG_OFF + ((t * 4 + g) * 8 + r) * 32;
        unsigned o = __hip_atomic_fetch_add(c0, 1u, __ATOMIC_RELAXED,
                                            __HIP_MEMORY_SCOPE_AGENT);
        if (o == 7u) {  // rail leader
            unsigned* c1 = bar + C1_OFF + (t * 4 + g) * 32;
            unsigned o2 = __hip_atomic_fetch_add(c1, 1u, __ATOMIC_RELAXED,
                                                 __HIP_MEMORY_SCOPE_AGENT);
            if (o2 == 7u) {  // last rail: release all 8 rails of (t,g)
#pragma unroll
                for (int rr = 0; rr < 8; ++rr)
                    __hip_atomic_store(bar + FLAG_OFF + ((t * 4 + g) * 8 + rr) * 32,
                                       1u, __ATOMIC_RELAXED, __HIP_MEMORY_SCOPE_AGENT);
            } else {
                while (!__hip_atomic_load(f, __ATOMIC_RELAXED,
                                          __HIP_MEMORY_SCOPE_AGENT))
                    __builtin_amdgcn_s_sleep(1);
            }
        } else {
            while (!__hip_atomic_load(f, __ATOMIC_RELAXED,
                                      __HIP_MEMORY_SCOPE_AGENT))
                __builtin_amdgcn_s_sleep(1);
        }
        asm volatile("" ::: "memory");
    }
    __syncthreads();
}

__device__ __forceinline__ float fast_tanh(float v) {
    return 1.0f - 2.0f / (__expf(2.0f * v) + 1.0f);
}

// ---- persistent RNN kernel: 256 blocks x 512 thr (8 waves, 2/SIMD) ----
__global__ void __launch_bounds__(512, 2) rnn_persist(
    const float* __restrict__ x,   // [B_,T_]
    const float* __restrict__ U,   // [H_]
    const float* __restrict__ W,   // [H_,H_] fp32
    const float* __restrict__ bh,  // [H_]
    half_t* __restrict__ hP0,      // packed state buf 0 (1 MB)
    half_t* __restrict__ hP1,      // packed state buf 1 (1 MB)
    float* __restrict__ hf32,      // d_out h_last region (row-major fp32)
    unsigned* __restrict__ bar)
{
    const int tid  = threadIdx.x;
    const int wave = tid >> 6, lane = tid & 63;
    const int quad = lane >> 4, lq = lane & 15;
    const int id   = blockIdx.x;
    const int grp  = id & 7;
    const int g    = grp >> 1, p = grp & 1;
    const int m0   = g * 64;                      // m-group g owns rows m0..m0+63
    const int C    = (id >> 3) * 2 + p;           // n-chunk 0..63; n0 = C*32
    const int n0   = C * 32;
    const int rail = (id >> 3) & 7;               // barrier sub-rail

    // ---- one-time: W frags for this wave's K-range -> 128 VGPRs ----
    half8 Bhi[8][2], Blo[8][2];
#pragma unroll
    for (int c = 0; c < 8; ++c) {
#pragma unroll
        for (int nt = 0; nt < 2; ++nt) {
            const int gn = n0 + nt * 16 + lq;
            const int k0 = (wave * 8 + c) * 32 + quad * 8;
            const float4 w0 = *(const float4*)&W[(size_t)gn * H_ + k0];
            const float4 w1 = *(const float4*)&W[(size_t)gn * H_ + k0 + 4];
            const float wv[8] = {w0.x, w0.y, w0.z, w0.w, w1.x, w1.y, w1.z, w1.w};
            half8 hi, lo;
#pragma unroll
            for (int j = 0; j < 8; ++j) {
                hi[j] = (half_t)wv[j];
                lo[j] = (half_t)(wv[j] - (float)hi[j]);
            }
            Bhi[c][nt] = hi;
            Blo[c][nt] = lo;
        }
    }

    // epilogue-owner role: wave w handles (msub, ntO)
    const int msub = wave & 3, ntO = wave >> 2;
    const float uvO = U[n0 + ntO * 16 + lq];
    const float bvO = bh[n0 + ntO * 16 + lq];

    __shared__ floatx4 red[4][8][2][64];          // 8-way k-split, 64 KB
    __shared__ float Sm[64][33];                  // epilogue transpose, 8.4 KB
    __shared__ float xs[T_][64];                  // x slab transposed, 32 KB

    for (int i = tid; i < 64 * T_; i += 512) {    // one-time x staging
        const int r = i & 63, tt = i >> 6;
        xs[tt][r] = x[(size_t)(m0 + r) * T_ + tt];
    }
    __syncthreads();

    // producer mapping: 512 thr x 1 u64 (4 halfs); u64 index = C*512 + tid
    const int prow = (tid >> 7) * 16 + ((tid >> 1) & 15);   // local row 0..63
    const int pcol = ((tid >> 5) & 3) * 8 + (tid & 1) * 4;  // local col base
    const size_t slab = (size_t)g * 32768;                  // u64 units
    const size_t pdst = slab + (size_t)C * 512 + tid;
    const size_t cbase = slab + (size_t)wave * 4096 + (size_t)lane * 2;

    // ---- step 0: h1 = tanh(x*U + bh) -> packed hP1 ----
    {
        const float xb = xs[0][prow];
        half4v hv;
#pragma unroll
        for (int j = 0; j < 4; ++j) {
            const int n = n0 + pcol + j;
            hv[j] = (half_t)fast_tanh(xb * U[n] + bh[n]);
        }
        __hip_atomic_store((u64*)hP1 + pdst, __builtin_bit_cast(u64, hv),
                           __ATOMIC_RELAXED, __HIP_MEMORY_SCOPE_AGENT);
    }
    step_barrier(bar, 0, g, rail);

    // ---- steps t = 1..127 ----
    for (int t = 1; t < T_; ++t) {
        const half_t* hin = (t & 1) ? hP1 : hP0;  // h_t (packed)
        half_t* hout      = (t & 1) ? hP0 : hP1;  // h_{t+1} (packed)
        const u64* pw = (const u64*)hin + cbase;

        floatx4 acc[4][2] = {};

        u64 rl[8], rh[8];                         // ring-8 of 16B frags
        auto issue = [&](int f) {
            const u64* q = pw + (size_t)((f >> 2) * 512 + (f & 3) * 128);
            rl[f & 7] = __hip_atomic_load(q, __ATOMIC_RELAXED,
                                          __HIP_MEMORY_SCOPE_AGENT);
            rh[f & 7] = __hip_atomic_load(q + 1, __ATOMIC_RELAXED,
                                          __HIP_MEMORY_SCOPE_AGENT);
        };
#pragma unroll
        for (int f = 0; f < 8; ++f) issue(f);
#pragma unroll
        for (int f = 0; f < 32; ++f) {            // c' = f>>2 in [0,8), mt = f&3
            const int c = f >> 2, mt = f & 3;
            u64x2 bits; bits.x = rl[f & 7]; bits.y = rh[f & 7];
            const half8 av = __builtin_bit_cast(half8, bits);
            if (f + 8 < 32) issue(f + 8);
            acc[mt][0] = __builtin_amdgcn_mfma_f32_16x16x32_f16(av, Bhi[c][0], acc[mt][0], 0, 0, 0);
            acc[mt][1] = __builtin_amdgcn_mfma_f32_16x16x32_f16(av, Bhi[c][1], acc[mt][1], 0, 0, 0);
            acc[mt][0] = __builtin_amdgcn_mfma_f32_16x16x32_f16(av, Blo[c][0], acc[mt][0], 0, 0, 0);
            acc[mt][1] = __builtin_amdgcn_mfma_f32_16x16x32_f16(av, Blo[c][1], acc[mt][1], 0, 0, 0);
        }

        // ---- 8-way K-split reduction ----
#pragma unroll
        for (int mt = 0; mt < 4; ++mt)
#pragma unroll
            for (int nt = 0; nt < 2; ++nt)
                red[mt][wave][nt][lane] = acc[mt][nt];
        __syncthreads();

        // owner wave: sum 8 partials, +x*U+bh, tanh -> Sm
        {
            float xr[4];
#pragma unroll
            for (int r = 0; r < 4; ++r) xr[r] = xs[t][msub * 16 + quad * 4 + r];
            floatx4 s = red[msub][0][ntO][lane];
#pragma unroll
            for (int ww = 1; ww < 8; ++ww) s += red[msub][ww][ntO][lane];
#pragma unroll
            for (int r = 0; r < 4; ++r) {
                const float pre = s[r] + xr[r] * uvO + bvO;
                Sm[msub * 16 + quad * 4 + r][ntO * 16 + lq] = fast_tanh(pre);
            }
        }
        __syncthreads();

        // publish: 1 u64 (4 halfs) per thread into the packed slab
        {
            float fv[4];
#pragma unroll
            for (int j = 0; j < 4; ++j) fv[j] = Sm[prow][pcol + j];
            half4v hv;
#pragma unroll
            for (int j = 0; j < 4; ++j) hv[j] = (half_t)fv[j];
            __hip_atomic_store((u64*)hout + pdst, __builtin_bit_cast(u64, hv),
                               __ATOMIC_RELAXED, __HIP_MEMORY_SCOPE_AGENT);
            if (t == T_ - 1) {  // final h_128 also to d_out, row-major fp32
                float* fd = hf32 + (size_t)(m0 + prow) * H_ + n0 + pcol;
                *(float4*)fd = make_float4(fv[0], fv[1], fv[2], fv[3]);
            }
        }
        if (t < T_ - 1) step_barrier(bar, t, g, rail);
    }
}

// ---- output projection: out[b,c] = h[b,:] . V[c,:] + bp[c] ----
__global__ __launch_bounds__(256) void rnn_out(
    const float* __restrict__ h, const float* __restrict__ V,
    const float* __restrict__ bp, float* __restrict__ outp) {
    const int b = blockIdx.x;
    const int tid = threadIdx.x;
    float acc[C_] = {};
    for (int k = tid; k < H_; k += 256) {
        const float hv = h[(size_t)b * H_ + k];
#pragma unroll
        for (int c = 0; c < C_; ++c) acc[c] += hv * V[(size_t)c * H_ + k];
    }
#pragma unroll
    for (int c = 0; c < C_; ++c)
#pragma unroll
        for (int off = 32; off > 0; off >>= 1)
            acc[c] += __shfl_down(acc[c], off, 64);
    __shared__ float partial[4][C_];
    const int wave = tid >> 6, lane = tid & 63;
    if (lane == 0)
#pragma unroll
        for (int c = 0; c < C_; ++c) partial[wave][c] = acc[c];
    __syncthreads();
    if (tid < C_)
        outp[b * C_ + tid] = partial[0][tid] + partial[1][tid]
                           + partial[2][tid] + partial[3][tid] + bp[tid];
}

extern "C" void kernel_launch(void* const* d_in, const int* in_sizes, int n_in,
                              void* d_out, int out_size, void* d_ws, size_t ws_size,
                              hipStream_t stream) {
    const float* x  = (const float*)d_in[0];
    const float* U  = (const float*)d_in[1];
    const float* W  = (const float*)d_in[2];
    const float* V  = (const float*)d_in[3];
    const float* bh = (const float*)d_in[4];
    const float* bp = (const float*)d_in[5];

    float* out_h = (float*)d_out;                 // [B_*H_] fp32 h_last
    float* outp  = out_h + (size_t)B_ * H_;       // [B_*C_]

    half_t* hP0 = (half_t*)d_ws;                                 // 1 MB packed
    half_t* hP1 = hP0 + (size_t)B_ * H_;                         // 1 MB packed
    unsigned* bar = (unsigned*)((char*)d_ws + 2u * 1024 * 1024); // ~1.06 MB

    hipMemsetAsync(bar, 0, BAR_DWORDS * sizeof(unsigned), stream);

    rnn_persist<<<dim3(256), dim3(512), 0, stream>>>(
        x, U, W, bh, hP0, hP1, out_h, bar);

    rnn_out<<<dim3(B_), dim3(256), 0, stream>>>(out_h, V, bp, outp);
}

// Round 12
// 1072.783 us; speedup vs baseline: 3.4380x; 1.0100x over previous
//
#include <hip/hip_runtime.h>
#include <cmath>

// VanillaRNN: B=256, T=128, D=1, H=2048, C=10
// R12: R11 (512-thr blocks, 2 waves/SIMD, packed sc1 h-exchange, W hi+lo
// fp16 in regs, 8-way K-split, per-producer data-ready flags) with the
// flag signal HARDENED: instead of one posted sc1 store, the producer's
// tid0 issues TWO CHAINED atomic fetch_adds on the flag line (the second's
// operand depends on the first's returned value, forcing a full MALL round
// trip between them; RMWs commit at the MALL). Consumers poll v >= 2.
// This gives the same release-path slack as the deterministic R10 barrier
// (R11's plain store could become visible while data write-through was
// still in flight -> occasional stale fragments -> tripwire divergence).
// Protocol recap: wave w consumes only producers C' in [8w,8w+8); it polls
// exactly those 8 flags (slot t-1) and starts its K-loop immediately.
// Overwrite safety is transitive through the pre-reduction __syncthreads.

#define B_ 256
#define T_ 128
#define H_ 2048
#define C_ 10

typedef _Float16 half_t;
typedef _Float16 half8 __attribute__((ext_vector_type(8)));
typedef _Float16 half4v __attribute__((ext_vector_type(4)));
typedef float floatx4 __attribute__((ext_vector_type(4)));
typedef unsigned long long u64;
typedef unsigned long long u64x2 __attribute__((ext_vector_type(2)));

// flag array: dword index  t*(4*64*32) + (g*64 + C)*32   (one 128B line per
// flag). t in [0,127), g in [0,4), C = producer block-in-group [0,64).
#define FLAG_DWORDS (128 * 4 * 64 * 32)   // 4 MB

__device__ __forceinline__ float fast_tanh(float v) {
    return 1.0f - 2.0f / (__expf(2.0f * v) + 1.0f);
}

// hardened release: two chained RMWs (2nd operand depends on 1st's result)
__device__ __forceinline__ void signal_flag(unsigned* fl) {
    unsigned o1 = __hip_atomic_fetch_add(fl, 1u, __ATOMIC_RELAXED,
                                         __HIP_MEMORY_SCOPE_AGENT);
    __hip_atomic_fetch_add(fl, 1u + (o1 >> 31), __ATOMIC_RELAXED,
                           __HIP_MEMORY_SCOPE_AGENT);
}

// ---- persistent RNN kernel: 256 blocks x 512 thr (8 waves, 2/SIMD) ----
__global__ void __launch_bounds__(512, 2) rnn_persist(
    const float* __restrict__ x,   // [B_,T_]
    const float* __restrict__ U,   // [H_]
    const float* __restrict__ W,   // [H_,H_] fp32
    const float* __restrict__ bh,  // [H_]
    half_t* __restrict__ hP0,      // packed state buf 0 (1 MB)
    half_t* __restrict__ hP1,      // packed state buf 1 (1 MB)
    float* __restrict__ hf32,      // d_out h_last region (row-major fp32)
    unsigned* __restrict__ flags)
{
    const int tid  = threadIdx.x;
    const int wave = tid >> 6, lane = tid & 63;
    const int quad = lane >> 4, lq = lane & 15;
    const int id   = blockIdx.x;
    const int grp  = id & 7;
    const int g    = grp >> 1, p = grp & 1;
    const int m0   = g * 64;                      // m-group g owns rows m0..m0+63
    const int C    = (id >> 3) * 2 + p;           // n-chunk 0..63 (= block-in-group)
    const int n0   = C * 32;

    // ---- one-time: W frags for this wave's K-range -> regs (hi+lo) ----
    half8 Bhi[8][2], Blo[8][2];
#pragma unroll
    for (int c = 0; c < 8; ++c) {
#pragma unroll
        for (int nt = 0; nt < 2; ++nt) {
            const int gn = n0 + nt * 16 + lq;
            const int k0 = (wave * 8 + c) * 32 + quad * 8;
            const float4 w0 = *(const float4*)&W[(size_t)gn * H_ + k0];
            const float4 w1 = *(const float4*)&W[(size_t)gn * H_ + k0 + 4];
            const float wv[8] = {w0.x, w0.y, w0.z, w0.w, w1.x, w1.y, w1.z, w1.w};
            half8 hi, lo;
#pragma unroll
            for (int j = 0; j < 8; ++j) {
                hi[j] = (half_t)wv[j];
                lo[j] = (half_t)(wv[j] - (float)hi[j]);
            }
            Bhi[c][nt] = hi;
            Blo[c][nt] = lo;
        }
    }

    // epilogue-owner role: wave w handles (msub, ntO)
    const int msub = wave & 3, ntO = wave >> 2;
    const float uvO = U[n0 + ntO * 16 + lq];
    const float bvO = bh[n0 + ntO * 16 + lq];

    __shared__ floatx4 red[4][8][2][64];          // 8-way k-split, 64 KB
    __shared__ float Sm[64][33];                  // epilogue transpose, 8.4 KB
    __shared__ float xs[T_][64];                  // x slab transposed, 32 KB

    for (int i = tid; i < 64 * T_; i += 512) {    // one-time x staging
        const int r = i & 63, tt = i >> 6;
        xs[tt][r] = x[(size_t)(m0 + r) * T_ + tt];
    }
    __syncthreads();

    // producer mapping (R10-validated): 512 thr x 1 u64 (4 halfs)
    const int prow = (tid >> 7) * 16 + ((tid >> 1) & 15);   // local row 0..63
    const int pcol = ((tid >> 5) & 3) * 8 + (tid & 1) * 4;  // local col base
    const size_t slab = (size_t)g * 32768;                  // u64 units
    const size_t pdst = slab + (size_t)C * 512 + tid;
    const size_t cbase = slab + (size_t)wave * 4096 + (size_t)lane * 2;

    // flag addresses
    unsigned* myflag_base = flags + ((size_t)g * 64 + C) * 32;     // + t*4*64*32
    const unsigned* pollp = flags + ((size_t)g * 64 + wave * 8 + (lane & 7)) * 32;

    // ---- step 0: h1 = tanh(x*U + bh) -> packed hP1, signal slot 0 ----
    {
        const float xb = xs[0][prow];
        half4v hv;
#pragma unroll
        for (int j = 0; j < 4; ++j) {
            const int n = n0 + pcol + j;
            hv[j] = (half_t)fast_tanh(xb * U[n] + bh[n]);
        }
        __hip_atomic_store((u64*)hP1 + pdst, __builtin_bit_cast(u64, hv),
                           __ATOMIC_RELAXED, __HIP_MEMORY_SCOPE_AGENT);
    }
    __syncthreads();                              // drain all lanes' publishes
    if (tid == 0) signal_flag(myflag_base);

    // ---- steps t = 1..127 ----
    for (int t = 1; t < T_; ++t) {
        const half_t* hin = (t & 1) ? hP1 : hP0;  // h_t (packed)
        half_t* hout      = (t & 1) ? hP0 : hP1;  // h_{t+1} (packed)
        const u64* pw = (const u64*)hin + cbase;

        // wave-level poll: my 8 producers for slot t-1 (hardened: v >= 2)
        {
            const unsigned* fp = pollp + (size_t)(t - 1) * (4 * 64 * 32);
            while (true) {
                const unsigned v = __hip_atomic_load(fp, __ATOMIC_RELAXED,
                                                     __HIP_MEMORY_SCOPE_AGENT);
                if (__all(v >= 2u)) break;
                __builtin_amdgcn_s_sleep(1);
            }
            asm volatile("" ::: "memory");        // no load hoisting above poll
        }

        floatx4 acc[4][2] = {};

        u64 rl[8], rh[8];                         // ring-8 of 16B frags
        auto issue = [&](int f) {
            const u64* q = pw + (size_t)((f >> 2) * 512 + (f & 3) * 128);
            rl[f & 7] = __hip_atomic_load(q, __ATOMIC_RELAXED,
                                          __HIP_MEMORY_SCOPE_AGENT);
            rh[f & 7] = __hip_atomic_load(q + 1, __ATOMIC_RELAXED,
                                          __HIP_MEMORY_SCOPE_AGENT);
        };
#pragma unroll
        for (int f = 0; f < 8; ++f) issue(f);
#pragma unroll
        for (int f = 0; f < 32; ++f) {            // c' = f>>2 in [0,8), mt = f&3
            const int c = f >> 2, mt = f & 3;
            u64x2 bits; bits.x = rl[f & 7]; bits.y = rh[f & 7];
            const half8 av = __builtin_bit_cast(half8, bits);
            if (f + 8 < 32) issue(f + 8);
            acc[mt][0] = __builtin_amdgcn_mfma_f32_16x16x32_f16(av, Bhi[c][0], acc[mt][0], 0, 0, 0);
            acc[mt][1] = __builtin_amdgcn_mfma_f32_16x16x32_f16(av, Bhi[c][1], acc[mt][1], 0, 0, 0);
            acc[mt][0] = __builtin_amdgcn_mfma_f32_16x16x32_f16(av, Blo[c][0], acc[mt][0], 0, 0, 0);
            acc[mt][1] = __builtin_amdgcn_mfma_f32_16x16x32_f16(av, Blo[c][1], acc[mt][1], 0, 0, 0);
        }

        // ---- 8-way K-split reduction ----
#pragma unroll
        for (int mt = 0; mt < 4; ++mt)
#pragma unroll
            for (int nt = 0; nt < 2; ++nt)
                red[mt][wave][nt][lane] = acc[mt][nt];
        __syncthreads();

        // owner wave: sum 8 partials, +x*U+bh, tanh -> Sm
        {
            float xr[4];
#pragma unroll
            for (int r = 0; r < 4; ++r) xr[r] = xs[t][msub * 16 + quad * 4 + r];
            floatx4 s = red[msub][0][ntO][lane];
#pragma unroll
            for (int ww = 1; ww < 8; ++ww) s += red[msub][ww][ntO][lane];
#pragma unroll
            for (int r = 0; r < 4; ++r) {
                const float pre = s[r] + xr[r] * uvO + bvO;
                Sm[msub * 16 + quad * 4 + r][ntO * 16 + lq] = fast_tanh(pre);
            }
        }
        __syncthreads();

        // publish: 1 u64 (4 halfs) per thread into the packed slab
        {
            float fv[4];
#pragma unroll
            for (int j = 0; j < 4; ++j) fv[j] = Sm[prow][pcol + j];
            half4v hv;
#pragma unroll
            for (int j = 0; j < 4; ++j) hv[j] = (half_t)fv[j];
            __hip_atomic_store((u64*)hout + pdst, __builtin_bit_cast(u64, hv),
                               __ATOMIC_RELAXED, __HIP_MEMORY_SCOPE_AGENT);
            if (t == T_ - 1) {  // final h_128 also to d_out, row-major fp32
                float* fd = hf32 + (size_t)(m0 + prow) * H_ + n0 + pcol;
                *(float4*)fd = make_float4(fv[0], fv[1], fv[2], fv[3]);
            }
        }
        if (t < T_ - 1) {
            __syncthreads();                      // drain publishes block-wide
            if (tid == 0)
                signal_flag(myflag_base + (size_t)t * (4 * 64 * 32));
        }
    }
}

// ---- output projection: out[b,c] = h[b,:] . V[c,:] + bp[c] ----
__global__ __launch_bounds__(256) void rnn_out(
    const float* __restrict__ h, const float* __restrict__ V,
    const float* __restrict__ bp, float* __restrict__ outp) {
    const int b = blockIdx.x;
    const int tid = threadIdx.x;
    float acc[C_] = {};
    for (int k = tid; k < H_; k += 256) {
        const float hv = h[(size_t)b * H_ + k];
#pragma unroll
        for (int c = 0; c < C_; ++c) acc[c] += hv * V[(size_t)c * H_ + k];
    }
#pragma unroll
    for (int c = 0; c < C_; ++c)
#pragma unroll
        for (int off = 32; off > 0; off >>= 1)
            acc[c] += __shfl_down(acc[c], off, 64);
    __shared__ float partial[4][C_];
    const int wave = tid >> 6, lane = tid & 63;
    if (lane == 0)
#pragma unroll
        for (int c = 0; c < C_; ++c) partial[wave][c] = acc[c];
    __syncthreads();
    if (tid < C_)
        outp[b * C_ + tid] = partial[0][tid] + partial[1][tid]
                           + partial[2][tid] + partial[3][tid] + bp[tid];
}

extern "C" void kernel_launch(void* const* d_in, const int* in_sizes, int n_in,
                              void* d_out, int out_size, void* d_ws, size_t ws_size,
                              hipStream_t stream) {
    const float* x  = (const float*)d_in[0];
    const float* U  = (const float*)d_in[1];
    const float* W  = (const float*)d_in[2];
    const float* V  = (const float*)d_in[3];
    const float* bh = (const float*)d_in[4];
    const float* bp = (const float*)d_in[5];

    float* out_h = (float*)d_out;                 // [B_*H_] fp32 h_last
    float* outp  = out_h + (size_t)B_ * H_;       // [B_*C_]

    half_t* hP0 = (half_t*)d_ws;                                   // 1 MB packed
    half_t* hP1 = hP0 + (size_t)B_ * H_;                           // 1 MB packed
    unsigned* flags = (unsigned*)((char*)d_ws + 2u * 1024 * 1024); // 4 MB

    hipMemsetAsync(flags, 0, FLAG_DWORDS * sizeof(unsigned), stream);

    rnn_persist<<<dim3(256), dim3(512), 0, stream>>>(
        x, U, W, bh, hP0, hP1, out_h, flags);

    rnn_out<<<dim3(B_), dim3(256), 0, stream>>>(out_h, V, bp, outp);
}